// Round 5
// baseline (55680.743 us; speedup 1.0000x reference)
//
#include <hip/hip_runtime.h>
#include <math.h>

#define FF 2048
#define NL 12
#define NB 16
#define TT 32
#define EPS 1e-5f
#define LOG2E 1.44269504088896f

#if __has_builtin(__builtin_amdgcn_exp2f)
#define EXP2(x) __builtin_amdgcn_exp2f(x)
#else
#define EXP2(x) exp2f(x)
#endif

typedef float v2f __attribute__((ext_vector_type(2)));
__device__ __forceinline__ v2f mk2(float x){ v2f r; r.x = x; r.y = x; return r; }

// ---------------------------------------------------------------------------
// Prepack into d_ws as w_all[24][4096] float4, f-PAIRED for packed math.
// ---------------------------------------------------------------------------
__global__ __launch_bounds__(256) void prepack_kernel(
    const float* __restrict__ enc_l1_w, const float* __restrict__ enc_l1_b,
    const float* __restrict__ enc_l2_w,
    const float* __restrict__ dec_l1_w, const float* __restrict__ dec_l1_b,
    const float* __restrict__ dec_l2_w,
    float4* __restrict__ w_all)
{
    int idx = blockIdx.x * blockDim.x + threadIdx.x;
    if (idx >= 24 * 1024) return;
    int lay = idx >> 10;
    int fp  = idx & 1023;
    int f0  = 2*fp, f1 = 2*fp + 1;
    const float *w1, *b1, *w2;
    if (lay < NL) {
        w1 = enc_l1_w + (size_t)lay * FF * 3;
        b1 = enc_l1_b + (size_t)lay * FF;
        w2 = enc_l2_w + (size_t)lay * 3 * FF;
    } else {
        int l = lay - NL;
        w1 = dec_l1_w + (size_t)l * FF * 3;
        b1 = dec_l1_b + (size_t)l * FF;
        w2 = dec_l2_w + (size_t)l * 3 * FF;
    }
    float4* base = w_all + (size_t)lay * 4096;
    base[fp]        = make_float4(w1[f0*3+0], w1[f1*3+0], w1[f0*3+1], w1[f1*3+1]);
    base[1024 + fp] = make_float4(w1[f0*3+2], w1[f1*3+2], b1[f0],     b1[f1]);
    base[2048 + fp] = make_float4(w2[f0],     w2[f1],     w2[FF+f0],  w2[FF+f1]);
    base[3072 + fp] = make_float4(w2[2*FF+f0], w2[2*FF+f1], 0.f, 0.f);
}

// ---------------------------------------------------------------------------
// Main kernel: one block per TWO batch elements, 1024 threads (16 waves).
// Software-pipelined 5-slot schedule; e1 lags e0 by 2 slots. All handoffs
// cross a __syncthreads(). Per group g (one layer for both elements):
//   slot 0: S0(e0,g)   | FFNh1(e1,g-1) | wv15: stage c3(layer g)
//   slot 1: S1(e0,g)   | FFNh2(e1,g-1) |
//   slot 2: S0(e1,g)   |               | wv15: stage c0(g+1) + CAproj(e0,g)
//   slot 3: S1(e1,g)   | FFNh1(e0,g)   | wv15: stage c1(g+1)
//   slot 4:            | FFNh2(e0,g)   | wv15: stage c2(g+1) + CAproj(e1,g)
// S0 = combine/O-fold -> X regs, write SA K/V (+ CA K/V from mem regs), SA.
// S1 = SA out-proj + LN1 -> B; enc: h0 writes x4; dec: write bb4, CA -> oo2.
// CAproj (wv15) = x4 = LN2(B + ca_ow*oo2)  (decoder only).
// Decoder outputs live in attn-wave O registers (R1-verified fold).
// ---------------------------------------------------------------------------
struct __align__(16) SharedMem {
    float4 wbuf[2][4096];      // double-buffered layer weights (128 KB)
    float4 x4[2][TT];          // FFN input / residual base
    float4 oo[2][TT];          // SA attention outputs {h0,h1,h2,-}
    float4 oo2[2][TT];         // CA attention outputs
    float4 bb4[2][TT];         // post-LN1 B (for wv15's CA out-proj)
    float  fred[2][TT][3][3];  // FFN partials: 3 per (elem, token, dim)
    float  kk[2][3][TT];       // self-attn keys, head-major
    float  vv[2][3][TT];       // self-attn values
    float  cak[2][3][TT];      // cross-attn keys (recomputed per layer)
    float  cav[2][3][TT];      // cross-attn values
};

__device__ __forceinline__ void ln3s(float y0, float y1, float y2,
    const float* __restrict__ w, const float* __restrict__ b,
    float& o0, float& o1, float& o2)
{
    float m  = (y0 + y1 + y2) * (1.0f / 3.0f);
    float d0 = y0 - m, d1 = y1 - m, d2 = y2 - m;
    float v  = (d0*d0 + d1*d1 + d2*d2) * (1.0f / 3.0f);
    float r  = __builtin_amdgcn_rsqf(v + EPS);
    o0 = d0 * r * w[0] + b[0];
    o1 = d1 * r * w[1] + b[1];
    o2 = d2 * r * w[2] + b[2];
}

template<int CTRL>
__device__ __forceinline__ float dpp_add(float v)
{
    int sh = __builtin_amdgcn_update_dpp(0, __float_as_int(v), CTRL, 0xF, 0xF, true);
    return v + __int_as_float(sh);
}

__device__ __forceinline__ float wave_sum64(float v)
{
    v = dpp_add<0x111>(v);
    v = dpp_add<0x112>(v);
    v = dpp_add<0x114>(v);
    v = dpp_add<0x118>(v);
    v = dpp_add<0x142>(v);
    v = dpp_add<0x143>(v);
    return v;   // valid in lane 63
}

__device__ __forceinline__ float fr3(const float* p) { return p[0] + p[1] + p[2]; }

// Halved-range softmax-attention (R0-proven). lanes 0-31: keys 0..15,
// lanes 32-63: keys 16..31; combine via shfl_xor(32). qs has log2e folded.
// MASK: whole 4-key blocks skipped when jbase >= ntok (R2/R3-verified).
template<bool MASK>
__device__ __forceinline__ float attn_half(float qs,
    const float* __restrict__ k, const float* __restrict__ v,
    int half, int ntok, int rep, float repw)
{
    const float4* k4 = (const float4*)k;
    const float4* v4 = (const float4*)v;
    float den0 = 0.f, den1 = 0.f, nv0 = 0.f, nv1 = 0.f;
    #pragma unroll
    for (int jb = 0; jb < 4; ++jb) {
        const int jbase = half*16 + jb*4;
        if (!MASK || jbase < ntok) {
            float4 kq = k4[half*4 + jb];
            float4 vq = v4[half*4 + jb];
            const float kj[4] = {kq.x, kq.y, kq.z, kq.w};
            const float vj[4] = {vq.x, vq.y, vq.z, vq.w};
            #pragma unroll
            for (int u = 0; u < 4; ++u) {
                float w = EXP2(qs * kj[u]);
                if (MASK) {
                    const int j = jbase + u;
                    w = (j < ntok) ? w : 0.f;
                    w = (j == rep) ? w * repw : w;
                }
                if (jb & 1) { den1 += w; nv1 = fmaf(w, vj[u], nv1); }
                else        { den0 += w; nv0 = fmaf(w, vj[u], nv0); }
            }
        }
    }
    float den = den0 + den1;
    float nv  = nv0 + nv1;
    den += __shfl_xor(den, 32, 64);
    nv  += __shfl_xor(nv , 32, 64);
    return nv * __builtin_amdgcn_rcpf(den);
}

// One f-pair column step of the FFN for NII tokens.
template<int NII>
__device__ __forceinline__ void ffn_jp(const float4* __restrict__ wb, int fp,
    const float (&X0)[8], const float (&X1)[8], const float (&X2)[8],
    v2f (&a0)[8], v2f (&a1)[8], v2f (&a2)[8])
{
    float4 A0 = wb[fp], A1 = wb[1024+fp];
    float4 C0 = wb[2048+fp], C1 = wb[3072+fp];
    v2f ax = {A0.x, A0.y}, ay = {A0.z, A0.w};
    v2f az = {A1.x, A1.y}, ab = {A1.z, A1.w};
    v2f cx = {C0.x, C0.y}, cy = {C0.z, C0.w};
    v2f cz = {C1.x, C1.y};
    const v2f z2 = {0.f, 0.f};
    #pragma unroll
    for (int ii = 0; ii < NII; ++ii) {
        v2f h2 = __builtin_elementwise_fma(ax, mk2(X0[ii]),
                 __builtin_elementwise_fma(ay, mk2(X1[ii]),
                 __builtin_elementwise_fma(az, mk2(X2[ii]), ab)));
        h2 = __builtin_elementwise_max(h2, z2);
        a0[ii] = __builtin_elementwise_fma(cx, h2, a0[ii]);
        a1[ii] = __builtin_elementwise_fma(cy, h2, a1[ii]);
        a2[ii] = __builtin_elementwise_fma(cz, h2, a2[ii]);
    }
}

// FFN half 1: load X, zero acc, columns jp=0..3 (fp = flane + 192*jp).
template<int NII>
__device__ __forceinline__ void ffn_h1(SharedMem& s, int e,
    const float4* __restrict__ wb, int gi, int flane,
    float (&X0)[8], float (&X1)[8], float (&X2)[8],
    v2f (&a0)[8], v2f (&a1)[8], v2f (&a2)[8])
{
    const v2f z2 = {0.f, 0.f};
    #pragma unroll
    for (int ii = 0; ii < NII; ++ii) {
        float4 xt = s.x4[e][gi + 4*ii];
        X0[ii] = xt.x; X1[ii] = xt.y; X2[ii] = xt.z;
        a0[ii] = z2; a1[ii] = z2; a2[ii] = z2;
    }
    #pragma unroll
    for (int jp = 0; jp < 4; ++jp)
        ffn_jp<NII>(wb, flane + 192*jp, X0, X1, X2, a0, a1, a2);
}

// FFN half 2: column jp=4 (+ jp=5 for w3==0), reduce + store fred.
template<int NII>
__device__ __forceinline__ void ffn_h2(SharedMem& s, int e,
    const float4* __restrict__ wb, int gi, int w3, int flane, int lane,
    float (&X0)[8], float (&X1)[8], float (&X2)[8],
    v2f (&a0)[8], v2f (&a1)[8], v2f (&a2)[8])
{
    ffn_jp<NII>(wb, flane + 768, X0, X1, X2, a0, a1, a2);
    if (flane < 64)
        ffn_jp<NII>(wb, flane + 960, X0, X1, X2, a0, a1, a2);
    #pragma unroll
    for (int ii = 0; ii < NII; ++ii) {
        const int t = gi + 4*ii;
        float r0 = wave_sum64(a0[ii].x + a0[ii].y);
        float r1 = wave_sum64(a1[ii].x + a1[ii].y);
        float r2 = wave_sum64(a2[ii].x + a2[ii].y);
        if (lane == 63) {
            s.fred[e][t][0][w3] = r0;
            s.fred[e][t][1][w3] = r1;
            s.fred[e][t][2][w3] = r2;
        }
    }
}

__global__ __launch_bounds__(1024, 4) void seq_kernel(
    const float* __restrict__ src, const float* __restrict__ angle,
    const float* __restrict__ enc_sa_w, const float* __restrict__ enc_sa_b,
    const float* __restrict__ enc_sa_ow, const float* __restrict__ enc_sa_ob,
    const float* __restrict__ enc_l2_b,
    const float* __restrict__ enc_n1_w, const float* __restrict__ enc_n1_b,
    const float* __restrict__ enc_n2_w, const float* __restrict__ enc_n2_b,
    const float* __restrict__ enc_nf_w, const float* __restrict__ enc_nf_b,
    const float* __restrict__ dec_sa_w, const float* __restrict__ dec_sa_b,
    const float* __restrict__ dec_sa_ow, const float* __restrict__ dec_sa_ob,
    const float* __restrict__ dec_ca_w, const float* __restrict__ dec_ca_b,
    const float* __restrict__ dec_ca_ow, const float* __restrict__ dec_ca_ob,
    const float* __restrict__ dec_l2_b,
    const float* __restrict__ dec_n1_w, const float* __restrict__ dec_n1_b,
    const float* __restrict__ dec_n2_w, const float* __restrict__ dec_n2_b,
    const float* __restrict__ dec_n3_w, const float* __restrict__ dec_n3_b,
    const float* __restrict__ dec_nf_w, const float* __restrict__ dec_nf_b,
    const float4* __restrict__ w_all,
    float* __restrict__ out)
{
    __shared__ SharedMem s;
    const int tid  = threadIdx.x;
    const int b0   = blockIdx.x * 2;
    const int wv   = tid >> 6;
    const int lane = tid & 63;
    const int q    = lane & 31;
    const int half = lane >> 5;

    // ---- init: stage encoder layer 0 weights + build inputs
    for (int k = tid; k < 4096; k += 1024)
        s.wbuf[0][k] = w_all[k];
    if (tid < 64) {
        const int e = tid >> 5;
        const int qq = tid & 31;
        float x0 = src[(b0 + e)*64 + qq];
        float x1 = src[(b0 + e)*64 + 32 + qq];
        float x2 = angle[b0 + e];
        s.x4[e][qq] = make_float4(x0, x1, x2, 0.f);
    }

    // attn-wave registers: embeds, decode outputs, encoder memory (per elem)
    float E00=0.f,E01=0.f,E02=0.f, E10=0.f,E11=0.f,E12=0.f;
    float O00=0.f,O01=0.f,O02=0.f, O10=0.f,O11=0.f,O12=0.f;
    float M00=0.f,M01=0.f,M02=0.f, M10=0.f,M11=0.f,M12=0.f;
    if (wv < 3) {
        E00 = src[b0*64 + q];       E01 = src[b0*64 + 32 + q];       E02 = angle[b0];
        E10 = src[(b0+1)*64 + q];   E11 = src[(b0+1)*64 + 32 + q];   E12 = angle[b0+1];
    }
    __syncthreads();

    // persistent state
    float X0=0.f, X1=0.f, X2=0.f;       // attn: S0 -> S1
    float fX0[8], fX1[8], fX2[8];        // FFN: h1 -> h2
    v2f  fa0[8], fa1[8], fa2[8];

    const int fw    = wv - 3;            // FFN wave index (valid wv 3..14)
    const int gi    = fw & 3;
    const int w3    = fw >> 2;
    const int flane = w3*64 + lane;

    // ------ stage S0: combine/O-fold -> X; SA (+CA K/V); -> oo[e] ------
    auto S0 = [&](int g, int e, float& M0, float& M1, float& M2,
                  float& Oa, float& Ob, float& Oc,
                  float Ea, float Eb, float Ec) {
        const int h = wv;
        if (g < 12) {
            float4 xa = s.x4[e][q];
            if (g == 0) { X0 = xa.x; X1 = xa.y; X2 = xa.z; }
            else {
                float f0 = fr3(s.fred[e][q][0]);
                float f1 = fr3(s.fred[e][q][1]);
                float f2 = fr3(s.fred[e][q][2]);
                ln3s(xa.x + f0 + enc_l2_b[(g-1)*3+0],
                     xa.y + f1 + enc_l2_b[(g-1)*3+1],
                     xa.z + f2 + enc_l2_b[(g-1)*3+2],
                     enc_n2_w + (g-1)*3, enc_n2_b + (g-1)*3, X0, X1, X2);
            }
            const float* saw = enc_sa_w + g*27;
            const float* sab = enc_sa_b + g*9;
            if (lane < 32) {
                s.kk[e][h][q] = sab[3+h] + saw[9+3*h]*X0  + saw[10+3*h]*X1 + saw[11+3*h]*X2;
                s.vv[e][h][q] = sab[6+h] + saw[18+3*h]*X0 + saw[19+3*h]*X1 + saw[20+3*h]*X2;
            }
            float qv = (sab[h] + saw[3*h]*X0 + saw[3*h+1]*X1 + saw[3*h+2]*X2) * LOG2E;
            float o = attn_half<false>(qv, &s.kk[e][h][0], &s.vv[e][h][0], half, TT, -1, 1.f);
            if (lane < 32) ((float*)&s.oo[e][q])[h] = o;
        } else {
            const int t = 1 + (g - 12) / 12;
            const int i = (g - 12) % 12;
            const int ntok = t + 1;
            if (g == 12) {
                // encoder tail -> M regs (lane q holds mem token q); O init
                float4 xa = s.x4[e][q];
                float f0 = fr3(s.fred[e][q][0]);
                float f1 = fr3(s.fred[e][q][1]);
                float f2 = fr3(s.fred[e][q][2]);
                float o0, o1, o2;
                ln3s(xa.x + f0 + enc_l2_b[33], xa.y + f1 + enc_l2_b[34],
                     xa.z + f2 + enc_l2_b[35], enc_n2_w + 33, enc_n2_b + 33,
                     o0, o1, o2);
                ln3s(o0, o1, o2, enc_nf_w, enc_nf_b, M0, M1, M2);
                Oa = (q == 0) ? Ea : 0.f;
                Ob = (q == 0) ? Eb : 0.f;
                Oc = (q == 0) ? Ec : 0.f;
                X0 = Oa; X1 = Ob; X2 = Oc;
            } else if (i == 0) {
                // step-tail fold: lane q==t-1 updates O from prev step
                if (q == t-1) {
                    float4 xa = s.x4[e][q];
                    float f0 = fr3(s.fred[e][q][0]);
                    float f1 = fr3(s.fred[e][q][1]);
                    float f2 = fr3(s.fred[e][q][2]);
                    float o0, o1, o2;
                    ln3s(xa.x + f0 + dec_l2_b[33], xa.y + f1 + dec_l2_b[34],
                         xa.z + f2 + dec_l2_b[35], dec_n3_w + 33, dec_n3_b + 33,
                         o0, o1, o2);
                    ln3s(o0, o1, o2, dec_nf_w, dec_nf_b, Oa, Ob, Oc);
                }
                const bool rl = (q <= t-1);
                X0 = rl ? Oa : 0.f; X1 = rl ? Ob : 0.f; X2 = rl ? Oc : 0.f;
            } else {
                float4 xa = s.x4[e][q];
                float f0 = fr3(s.fred[e][q][0]);
                float f1 = fr3(s.fred[e][q][1]);
                float f2 = fr3(s.fred[e][q][2]);
                ln3s(xa.x + f0 + dec_l2_b[(i-1)*3+0],
                     xa.y + f1 + dec_l2_b[(i-1)*3+1],
                     xa.z + f2 + dec_l2_b[(i-1)*3+2],
                     dec_n3_w + (i-1)*3, dec_n3_b + (i-1)*3, X0, X1, X2);
            }
            const float* saw = dec_sa_w + i*27;
            const float* sab = dec_sa_b + i*9;
            const float* caw = dec_ca_w + i*27;
            const float* cab = dec_ca_b + i*9;
            if (lane < 32) {
                if (q < ntok) {
                    s.kk[e][h][q] = sab[3+h] + saw[9+3*h]*X0  + saw[10+3*h]*X1 + saw[11+3*h]*X2;
                    s.vv[e][h][q] = sab[6+h] + saw[18+3*h]*X0 + saw[19+3*h]*X1 + saw[20+3*h]*X2;
                }
                // CA K/V for this layer from per-lane mem registers
                s.cak[e][h][q] = cab[3+h] + caw[(3+h)*3]*M0 + caw[(3+h)*3+1]*M1 + caw[(3+h)*3+2]*M2;
                s.cav[e][h][q] = cab[6+h] + caw[(6+h)*3]*M0 + caw[(6+h)*3+1]*M1 + caw[(6+h)*3+2]*M2;
            }
            float qv = (sab[h] + saw[3*h]*X0 + saw[3*h+1]*X1 + saw[3*h+2]*X2) * LOG2E;
            float o = attn_half<true>(qv, &s.kk[e][h][0], &s.vv[e][h][0],
                                      half, ntok, t, (float)(TT - t));
            if (lane < 32 && q < ntok) ((float*)&s.oo[e][q])[h] = o;
        }
    };

    // ------ stage S1: SA out-proj + LN1 -> B; enc: x4; dec: bb4 + CA ------
    auto S1 = [&](int g, int e) {
        const int h = wv;
        float4 ov = s.oo[e][q];
        if (g < 12) {
            const float* saow = enc_sa_ow + g*9;
            const float* saob = enc_sa_ob + g*3;
            float y0 = X0 + saob[0] + saow[0]*ov.x + saow[1]*ov.y + saow[2]*ov.z;
            float y1 = X1 + saob[1] + saow[3]*ov.x + saow[4]*ov.y + saow[5]*ov.z;
            float y2 = X2 + saob[2] + saow[6]*ov.x + saow[7]*ov.y + saow[8]*ov.z;
            float B0, B1, B2;
            ln3s(y0, y1, y2, enc_n1_w + g*3, enc_n1_b + g*3, B0, B1, B2);
            if (h == 0 && lane < 32)
                s.x4[e][q] = make_float4(B0, B1, B2, 0.f);
        } else {
            const int t = 1 + (g - 12) / 12;
            const int i = (g - 12) % 12;
            const int ntok = t + 1;
            const float* saow = dec_sa_ow + i*9;
            const float* saob = dec_sa_ob + i*3;
            float y0 = X0 + saob[0] + saow[0]*ov.x + saow[1]*ov.y + saow[2]*ov.z;
            float y1 = X1 + saob[1] + saow[3]*ov.x + saow[4]*ov.y + saow[5]*ov.z;
            float y2 = X2 + saob[2] + saow[6]*ov.x + saow[7]*ov.y + saow[8]*ov.z;
            float B0, B1, B2;
            ln3s(y0, y1, y2, dec_n1_w + i*3, dec_n1_b + i*3, B0, B1, B2);
            if (h == 0 && lane < 32 && q < ntok)
                s.bb4[e][q] = make_float4(B0, B1, B2, 0.f);
            const float* caw = dec_ca_w + i*27;
            const float* cab = dec_ca_b + i*9;
            float cqv = (cab[h] + caw[3*h]*B0 + caw[3*h+1]*B1 + caw[3*h+2]*B2) * LOG2E;
            float oc = attn_half<false>(cqv, &s.cak[e][h][0], &s.cav[e][h][0],
                                        half, TT, -1, 1.f);
            if (lane < 32 && q < ntok) ((float*)&s.oo2[e][q])[h] = oc;
        }
    };

    // ------ CA out-proj + LN2 -> x4 (staging wave, decoder only) ------
    auto CAPROJ = [&](int g, int e) {
        const int t = 1 + (g - 12) / 12;
        const int i = (g - 12) % 12;
        const int ntok = t + 1;
        if (lane < ntok) {
            float4 bb = s.bb4[e][lane];
            float4 c2 = s.oo2[e][lane];
            const float* caow = dec_ca_ow + i*9;
            const float* caob = dec_ca_ob + i*3;
            float y0 = bb.x + caob[0] + caow[0]*c2.x + caow[1]*c2.y + caow[2]*c2.z;
            float y1 = bb.y + caob[1] + caow[3]*c2.x + caow[4]*c2.y + caow[5]*c2.z;
            float y2 = bb.z + caob[2] + caow[6]*c2.x + caow[7]*c2.y + caow[8]*c2.z;
            float A0, A1, A2;
            ln3s(y0, y1, y2, dec_n2_w + i*3, dec_n2_b + i*3, A0, A1, A2);
            s.x4[e][lane] = make_float4(A0, A1, A2, 0.f);
        }
    };

    // ------ FFN half dispatch ------
    auto FFN = [&](int L, int e, int hf) {
        const int ntokF = (L < 12) ? TT : (2 + (L - 12) / 12);
        const float4* wb = s.wbuf[L & 1];
        if (hf == 1) {
            if (ntokF <= 8)       ffn_h1<2>(s, e, wb, gi, flane, fX0, fX1, fX2, fa0, fa1, fa2);
            else if (ntokF <= 16) ffn_h1<4>(s, e, wb, gi, flane, fX0, fX1, fX2, fa0, fa1, fa2);
            else                  ffn_h1<8>(s, e, wb, gi, flane, fX0, fX1, fX2, fa0, fa1, fa2);
        } else {
            if (ntokF <= 8)       ffn_h2<2>(s, e, wb, gi, w3, flane, lane, fX0, fX1, fX2, fa0, fa1, fa2);
            else if (ntokF <= 16) ffn_h2<4>(s, e, wb, gi, w3, flane, lane, fX0, fX1, fX2, fa0, fa1, fa2);
            else                  ffn_h2<8>(s, e, wb, gi, w3, flane, lane, fX0, fX1, fX2, fa0, fa1, fa2);
        }
    };

    // ------ stage one 16KB weight column (wv15) ------
    auto STAGE = [&](int L, int c) {
        const int wi = (L < 12) ? L : 12 + (L - 12) % 12;
        const float4* sp = w_all + (size_t)wi * 4096 + c * 1024;
        float4* dp = s.wbuf[L & 1] + c * 1024;
        #pragma unroll 4
        for (int j = 0; j < 16; ++j)
            dp[j*64 + lane] = sp[j*64 + lane];
    };

    // ------ main pipelined loop ------
    for (int g = 0; g <= 384; ++g) {
        const int ns = (g < 384) ? 5 : 2;
        for (int sl = 0; sl < ns; ++sl) {
            if (wv < 3) {
                if (g < 384) {
                    if (sl == 0)      S0(g, 0, M00,M01,M02, O00,O01,O02, E00,E01,E02);
                    else if (sl == 1) S1(g, 0);
                    else if (sl == 2) S0(g, 1, M10,M11,M12, O10,O11,O12, E10,E11,E12);
                    else if (sl == 3) S1(g, 1);
                }
            } else if (wv < 15) {
                if (sl == 0)      { if (g >= 1) FFN(g - 1, 1, 1); }
                else if (sl == 1) { if (g >= 1) FFN(g - 1, 1, 2); }
                else if (sl == 3) FFN(g, 0, 1);
                else if (sl == 4) FFN(g, 0, 2);
            } else {
                if (sl == 0) {
                    if (g >= 1 && g <= 383) STAGE(g, 3);
                } else if (sl == 2) {
                    if (g + 1 <= 383) STAGE(g + 1, 0);
                    if (g >= 12 && g < 384) CAPROJ(g, 0);
                } else if (sl == 3) {
                    if (g + 1 <= 383) STAGE(g + 1, 1);
                } else if (sl == 4) {
                    if (g + 1 <= 383) STAGE(g + 1, 2);
                    if (g >= 12 && g < 384) CAPROJ(g, 1);
                }
            }
            __syncthreads();
        }
    }

    // ---- final token-31 updates + output writes
    if (wv < 3) {
        if (q == 31) {
            {
                float4 xa = s.x4[0][31];
                float f0 = fr3(s.fred[0][31][0]);
                float f1 = fr3(s.fred[0][31][1]);
                float f2 = fr3(s.fred[0][31][2]);
                float o0, o1, o2;
                ln3s(xa.x + f0 + dec_l2_b[33], xa.y + f1 + dec_l2_b[34],
                     xa.z + f2 + dec_l2_b[35], dec_n3_w + 33, dec_n3_b + 33,
                     o0, o1, o2);
                ln3s(o0, o1, o2, dec_nf_w, dec_nf_b, O00, O01, O02);
            }
            {
                float4 xa = s.x4[1][31];
                float f0 = fr3(s.fred[1][31][0]);
                float f1 = fr3(s.fred[1][31][1]);
                float f2 = fr3(s.fred[1][31][2]);
                float o0, o1, o2;
                ln3s(xa.x + f0 + dec_l2_b[33], xa.y + f1 + dec_l2_b[34],
                     xa.z + f2 + dec_l2_b[35], dec_n3_w + 33, dec_n3_b + 33,
                     o0, o1, o2);
                ln3s(o0, o1, o2, dec_nf_w, dec_nf_b, O10, O11, O12);
            }
        }
        if (wv == 0 && lane < 32) {
            out[b0*96 +  0 + q] = O00;
            out[b0*96 + 32 + q] = O01;
            out[b0*96 + 64 + q] = O02;
            out[(b0+1)*96 +  0 + q] = O10;
            out[(b0+1)*96 + 32 + q] = O11;
            out[(b0+1)*96 + 64 + q] = O12;
        }
    }
}

extern "C" void kernel_launch(void* const* d_in, const int* in_sizes, int n_in,
                              void* d_out, int out_size, void* d_ws, size_t ws_size,
                              hipStream_t stream) {
    const float* src      = (const float*)d_in[0];
    const float* angle    = (const float*)d_in[1];
    const float* enc_sa_w = (const float*)d_in[2];
    const float* enc_sa_b = (const float*)d_in[3];
    const float* enc_sa_ow= (const float*)d_in[4];
    const float* enc_sa_ob= (const float*)d_in[5];
    const float* enc_l1_w = (const float*)d_in[6];
    const float* enc_l1_b = (const float*)d_in[7];
    const float* enc_l2_w = (const float*)d_in[8];
    const float* enc_l2_b = (const float*)d_in[9];
    const float* enc_n1_w = (const float*)d_in[10];
    const float* enc_n1_b = (const float*)d_in[11];
    const float* enc_n2_w = (const float*)d_in[12];
    const float* enc_n2_b = (const float*)d_in[13];
    const float* enc_nf_w = (const float*)d_in[14];
    const float* enc_nf_b = (const float*)d_in[15];
    const float* dec_sa_w = (const float*)d_in[16];
    const float* dec_sa_b = (const float*)d_in[17];
    const float* dec_sa_ow= (const float*)d_in[18];
    const float* dec_sa_ob= (const float*)d_in[19];
    const float* dec_ca_w = (const float*)d_in[20];
    const float* dec_ca_b = (const float*)d_in[21];
    const float* dec_ca_ow= (const float*)d_in[22];
    const float* dec_ca_ob= (const float*)d_in[23];
    const float* dec_l1_w = (const float*)d_in[24];
    const float* dec_l1_b = (const float*)d_in[25];
    const float* dec_l2_w = (const float*)d_in[26];
    const float* dec_l2_b = (const float*)d_in[27];
    const float* dec_n1_w = (const float*)d_in[28];
    const float* dec_n1_b = (const float*)d_in[29];
    const float* dec_n2_w = (const float*)d_in[30];
    const float* dec_n2_b = (const float*)d_in[31];
    const float* dec_n3_w = (const float*)d_in[32];
    const float* dec_n3_b = (const float*)d_in[33];
    const float* dec_nf_w = (const float*)d_in[34];
    const float* dec_nf_b = (const float*)d_in[35];

    float4* w_all = (float4*)d_ws;

    prepack_kernel<<<(24 * 1024 + 255) / 256, 256, 0, stream>>>(
        enc_l1_w, enc_l1_b, enc_l2_w,
        dec_l1_w, dec_l1_b, dec_l2_w,
        w_all);

    seq_kernel<<<NB/2, 1024, 0, stream>>>(
        src, angle,
        enc_sa_w, enc_sa_b, enc_sa_ow, enc_sa_ob, enc_l2_b,
        enc_n1_w, enc_n1_b, enc_n2_w, enc_n2_b, enc_nf_w, enc_nf_b,
        dec_sa_w, dec_sa_b, dec_sa_ow, dec_sa_ob,
        dec_ca_w, dec_ca_b, dec_ca_ow, dec_ca_ob, dec_l2_b,
        dec_n1_w, dec_n1_b, dec_n2_w, dec_n2_b, dec_n3_w, dec_n3_b,
        dec_nf_w, dec_nf_b,
        (const float4*)w_all,
        (float*)d_out);
}

// Round 6
// 3280.634 us; speedup vs baseline: 16.9726x; 16.9726x over previous
//
#include <hip/hip_runtime.h>
#include <math.h>

#define FF 2048
#define NL 12
#define NB 16
#define TT 32
#define EPS 1e-5f
#define LOG2E 1.44269504088896f

#if __has_builtin(__builtin_amdgcn_exp2f)
#define EXP2(x) __builtin_amdgcn_exp2f(x)
#else
#define EXP2(x) exp2f(x)
#endif

typedef float v2f __attribute__((ext_vector_type(2)));
__device__ __forceinline__ v2f mk2(float x){ v2f r; r.x = x; r.y = x; return r; }

// ---------------------------------------------------------------------------
// Prepack into d_ws as w_all[24][4096] float4, f-PAIRED for packed math.
// ---------------------------------------------------------------------------
__global__ __launch_bounds__(256) void prepack_kernel(
    const float* __restrict__ enc_l1_w, const float* __restrict__ enc_l1_b,
    const float* __restrict__ enc_l2_w,
    const float* __restrict__ dec_l1_w, const float* __restrict__ dec_l1_b,
    const float* __restrict__ dec_l2_w,
    float4* __restrict__ w_all)
{
    int idx = blockIdx.x * blockDim.x + threadIdx.x;
    if (idx >= 24 * 1024) return;
    int lay = idx >> 10;
    int fp  = idx & 1023;
    int f0  = 2*fp, f1 = 2*fp + 1;
    const float *w1, *b1, *w2;
    if (lay < NL) {
        w1 = enc_l1_w + (size_t)lay * FF * 3;
        b1 = enc_l1_b + (size_t)lay * FF;
        w2 = enc_l2_w + (size_t)lay * 3 * FF;
    } else {
        int l = lay - NL;
        w1 = dec_l1_w + (size_t)l * FF * 3;
        b1 = dec_l1_b + (size_t)l * FF;
        w2 = dec_l2_w + (size_t)l * 3 * FF;
    }
    float4* base = w_all + (size_t)lay * 4096;
    base[fp]        = make_float4(w1[f0*3+0], w1[f1*3+0], w1[f0*3+1], w1[f1*3+1]);
    base[1024 + fp] = make_float4(w1[f0*3+2], w1[f1*3+2], b1[f0],     b1[f1]);
    base[2048 + fp] = make_float4(w2[f0],     w2[f1],     w2[FF+f0],  w2[FF+f1]);
    base[3072 + fp] = make_float4(w2[2*FF+f0], w2[2*FF+f1], 0.f, 0.f);
}

// ---------------------------------------------------------------------------
// Main kernel: one block per TWO batch elements, 1024 threads (16 waves).
// 2-slot staggered schedule per group g (= layer g for both elements):
//   slot 0: wv0: full attn-layer(e0,g) | wv2-13: full FFN(e1,g-1)
//           | wv14-15: stage half B of layer g.                 barrier
//   slot 1: wv1: full attn-layer(e1,g) | wv2-13: full FFN(e0,g)
//           | wv14-15: stage half A of layer g+1.               barrier
// Every slot is SELF-CONTAINED: no per-thread state lives across barriers
// (the R5 failure mode). Attn is fully in-wave (R1-verified serial 3-head
// structure, incl. CA from per-lane M regs); its latency hides under the
// other element's FFN. Decoder outputs live in the attn wave's O registers.
// ---------------------------------------------------------------------------
struct __align__(16) SharedMem {
    float4 wbuf[2][4096];      // double-buffered layer weights (128 KB)
    float4 x4[2][TT];          // FFN input / residual base per element
    float  fred[2][TT][3][3];  // FFN partials: 3 per (elem, token, dim)
    float  kk[2][3][TT];       // self-attn keys, head-major
    float  vv[2][3][TT];       // self-attn values
    float  cak[2][3][TT];      // cross-attn keys (recomputed per layer)
    float  cav[2][3][TT];      // cross-attn values
};

__device__ __forceinline__ void ln3s(float y0, float y1, float y2,
    const float* __restrict__ w, const float* __restrict__ b,
    float& o0, float& o1, float& o2)
{
    float m  = (y0 + y1 + y2) * (1.0f / 3.0f);
    float d0 = y0 - m, d1 = y1 - m, d2 = y2 - m;
    float v  = (d0*d0 + d1*d1 + d2*d2) * (1.0f / 3.0f);
    float r  = __builtin_amdgcn_rsqf(v + EPS);
    o0 = d0 * r * w[0] + b[0];
    o1 = d1 * r * w[1] + b[1];
    o2 = d2 * r * w[2] + b[2];
}

template<int CTRL>
__device__ __forceinline__ float dpp_add(float v)
{
    int sh = __builtin_amdgcn_update_dpp(0, __float_as_int(v), CTRL, 0xF, 0xF, true);
    return v + __int_as_float(sh);
}

__device__ __forceinline__ float wave_sum64(float v)
{
    v = dpp_add<0x111>(v);
    v = dpp_add<0x112>(v);
    v = dpp_add<0x114>(v);
    v = dpp_add<0x118>(v);
    v = dpp_add<0x142>(v);
    v = dpp_add<0x143>(v);
    return v;   // valid in lane 63
}

__device__ __forceinline__ float fr3(const float* p) { return p[0] + p[1] + p[2]; }

// Halved-range softmax-attention (R0-proven). lanes 0-31: keys 0..15,
// lanes 32-63: keys 16..31; combine via shfl_xor(32). qs has log2e folded.
template<bool MASK>
__device__ __forceinline__ float attn_half(float qs,
    const float* __restrict__ k, const float* __restrict__ v,
    int half, int ntok, int rep, float repw)
{
    const float4* k4 = (const float4*)k;
    const float4* v4 = (const float4*)v;
    float den0 = 0.f, den1 = 0.f, nv0 = 0.f, nv1 = 0.f;
    #pragma unroll
    for (int jb = 0; jb < 4; ++jb) {
        const int jbase = half*16 + jb*4;
        if (!MASK || jbase < ntok) {
            float4 kq = k4[half*4 + jb];
            float4 vq = v4[half*4 + jb];
            const float kj[4] = {kq.x, kq.y, kq.z, kq.w};
            const float vj[4] = {vq.x, vq.y, vq.z, vq.w};
            #pragma unroll
            for (int u = 0; u < 4; ++u) {
                float w = EXP2(qs * kj[u]);
                if (MASK) {
                    const int j = jbase + u;
                    w = (j < ntok) ? w : 0.f;
                    w = (j == rep) ? w * repw : w;
                }
                if (jb & 1) { den1 += w; nv1 = fmaf(w, vj[u], nv1); }
                else        { den0 += w; nv0 = fmaf(w, vj[u], nv0); }
            }
        }
    }
    float den = den0 + den1;
    float nv  = nv0 + nv1;
    den += __shfl_xor(den, 32, 64);
    nv  += __shfl_xor(nv , 32, 64);
    return nv * __builtin_amdgcn_rcpf(den);
}

// One f-pair column step of the FFN for NII tokens.
template<int NII>
__device__ __forceinline__ void ffn_jp(const float4* __restrict__ wb, int fp,
    const float (&X0)[NII], const float (&X1)[NII], const float (&X2)[NII],
    v2f (&a0)[NII], v2f (&a1)[NII], v2f (&a2)[NII])
{
    float4 A0 = wb[fp], A1 = wb[1024+fp];
    float4 C0 = wb[2048+fp], C1 = wb[3072+fp];
    v2f ax = {A0.x, A0.y}, ay = {A0.z, A0.w};
    v2f az = {A1.x, A1.y}, ab = {A1.z, A1.w};
    v2f cx = {C0.x, C0.y}, cy = {C0.z, C0.w};
    v2f cz = {C1.x, C1.y};
    const v2f z2 = {0.f, 0.f};
    #pragma unroll
    for (int ii = 0; ii < NII; ++ii) {
        v2f h2 = __builtin_elementwise_fma(ax, mk2(X0[ii]),
                 __builtin_elementwise_fma(ay, mk2(X1[ii]),
                 __builtin_elementwise_fma(az, mk2(X2[ii]), ab)));
        h2 = __builtin_elementwise_max(h2, z2);
        a0[ii] = __builtin_elementwise_fma(cx, h2, a0[ii]);
        a1[ii] = __builtin_elementwise_fma(cy, h2, a1[ii]);
        a2[ii] = __builtin_elementwise_fma(cz, h2, a2[ii]);
    }
}

// Self-contained FFN pass over tokens {gi+4*(ii0+ii) : ii<NII}: load X,
// all 1024/192 column steps, reduce, store fred. Lives entirely in one slot.
template<int NII>
__device__ __forceinline__ void ffn_pass(SharedMem& s, int e,
    const float4* __restrict__ wb, int gi, int w3, int flane, int lane, int ii0)
{
    const v2f z2 = {0.f, 0.f};
    float X0[NII], X1[NII], X2[NII];
    v2f a0[NII], a1[NII], a2[NII];
    #pragma unroll
    for (int ii = 0; ii < NII; ++ii) {
        float4 xt = s.x4[e][gi + 4*(ii0 + ii)];
        X0[ii] = xt.x; X1[ii] = xt.y; X2[ii] = xt.z;
        a0[ii] = z2; a1[ii] = z2; a2[ii] = z2;
    }
    #pragma unroll
    for (int jp = 0; jp < 5; ++jp)
        ffn_jp<NII>(wb, flane + 192*jp, X0, X1, X2, a0, a1, a2);
    if (flane < 64)
        ffn_jp<NII>(wb, flane + 960, X0, X1, X2, a0, a1, a2);
    #pragma unroll
    for (int ii = 0; ii < NII; ++ii) {
        const int t = gi + 4*(ii0 + ii);
        float r0 = wave_sum64(a0[ii].x + a0[ii].y);
        float r1 = wave_sum64(a1[ii].x + a1[ii].y);
        float r2 = wave_sum64(a2[ii].x + a2[ii].y);
        if (lane == 63) {
            s.fred[e][t][0][w3] = r0;
            s.fred[e][t][1][w3] = r1;
            s.fred[e][t][2][w3] = r2;
        }
    }
}

__global__ __launch_bounds__(1024, 4) void seq_kernel(
    const float* __restrict__ src, const float* __restrict__ angle,
    const float* __restrict__ enc_sa_w, const float* __restrict__ enc_sa_b,
    const float* __restrict__ enc_sa_ow, const float* __restrict__ enc_sa_ob,
    const float* __restrict__ enc_l2_b,
    const float* __restrict__ enc_n1_w, const float* __restrict__ enc_n1_b,
    const float* __restrict__ enc_n2_w, const float* __restrict__ enc_n2_b,
    const float* __restrict__ enc_nf_w, const float* __restrict__ enc_nf_b,
    const float* __restrict__ dec_sa_w, const float* __restrict__ dec_sa_b,
    const float* __restrict__ dec_sa_ow, const float* __restrict__ dec_sa_ob,
    const float* __restrict__ dec_ca_w, const float* __restrict__ dec_ca_b,
    const float* __restrict__ dec_ca_ow, const float* __restrict__ dec_ca_ob,
    const float* __restrict__ dec_l2_b,
    const float* __restrict__ dec_n1_w, const float* __restrict__ dec_n1_b,
    const float* __restrict__ dec_n2_w, const float* __restrict__ dec_n2_b,
    const float* __restrict__ dec_n3_w, const float* __restrict__ dec_n3_b,
    const float* __restrict__ dec_nf_w, const float* __restrict__ dec_nf_b,
    const float4* __restrict__ w_all,
    float* __restrict__ out)
{
    __shared__ SharedMem s;
    const int tid  = threadIdx.x;
    const int b0   = blockIdx.x * 2;
    const int wv   = tid >> 6;
    const int lane = tid & 63;
    const int q    = lane & 31;
    const int half = lane >> 5;

    // ---- init: stage encoder layer 0 weights + build inputs
    for (int k = tid; k < 4096; k += 1024)
        s.wbuf[0][k] = w_all[k];
    if (tid < 64) {
        const int e = tid >> 5;
        const int qq = tid & 31;
        float x0 = src[(b0 + e)*64 + qq];
        float x1 = src[(b0 + e)*64 + 32 + qq];
        float x2 = angle[b0 + e];
        s.x4[e][qq] = make_float4(x0, x1, x2, 0.f);
    }

    // attn-wave per-element registers (wave wv owns element wv, wv < 2)
    float E0=0.f,E1=0.f,E2=0.f;   // embeds (token q)
    float O0=0.f,O1=0.f,O2=0.f;   // decode outputs (token q)
    float M0=0.f,M1=0.f,M2=0.f;   // encoder memory (token q)
    if (wv < 2) {
        E0 = src[(b0+wv)*64 + q];
        E1 = src[(b0+wv)*64 + 32 + q];
        E2 = angle[b0+wv];
    }
    __syncthreads();

    const int fw    = wv - 2;            // FFN wave index (valid wv 2..13)
    const int gi    = fw & 3;
    const int w3    = fw >> 2;
    const int flane = w3*64 + lane;

    // ------ full attn-layer for element e==wv (one wave, R1 structure) ------
    auto ATTN = [&](int g) {
        const int e = wv;
        float X0, X1, X2;
        __builtin_amdgcn_s_setprio(1);
        if (g < 12) {
            float4 xa = s.x4[e][q];
            if (g == 0) { X0 = xa.x; X1 = xa.y; X2 = xa.z; }
            else {
                float f0 = fr3(s.fred[e][q][0]);
                float f1 = fr3(s.fred[e][q][1]);
                float f2 = fr3(s.fred[e][q][2]);
                ln3s(xa.x + f0 + enc_l2_b[(g-1)*3+0],
                     xa.y + f1 + enc_l2_b[(g-1)*3+1],
                     xa.z + f2 + enc_l2_b[(g-1)*3+2],
                     enc_n2_w + (g-1)*3, enc_n2_b + (g-1)*3, X0, X1, X2);
            }
            const float* saw = enc_sa_w + g*27;
            const float* sab = enc_sa_b + g*9;
            if (lane < 32) {
                #pragma unroll
                for (int h = 0; h < 3; ++h) {
                    s.kk[e][h][q] = sab[3+h] + saw[9+3*h]*X0  + saw[10+3*h]*X1 + saw[11+3*h]*X2;
                    s.vv[e][h][q] = sab[6+h] + saw[18+3*h]*X0 + saw[19+3*h]*X1 + saw[20+3*h]*X2;
                }
            }
            float oh[3];
            #pragma unroll
            for (int h = 0; h < 3; ++h) {
                float qv = (sab[h] + saw[3*h]*X0 + saw[3*h+1]*X1 + saw[3*h+2]*X2) * LOG2E;
                oh[h] = attn_half<false>(qv, &s.kk[e][h][0], &s.vv[e][h][0], half, TT, -1, 1.f);
            }
            const float* saow = enc_sa_ow + g*9;
            const float* saob = enc_sa_ob + g*3;
            float y0 = X0 + saob[0] + saow[0]*oh[0] + saow[1]*oh[1] + saow[2]*oh[2];
            float y1 = X1 + saob[1] + saow[3]*oh[0] + saow[4]*oh[1] + saow[5]*oh[2];
            float y2 = X2 + saob[2] + saow[6]*oh[0] + saow[7]*oh[1] + saow[8]*oh[2];
            float B0, B1, B2;
            ln3s(y0, y1, y2, enc_n1_w + g*3, enc_n1_b + g*3, B0, B1, B2);
            if (lane < 32) s.x4[e][q] = make_float4(B0, B1, B2, 0.f);
        } else {
            const int t = 1 + (g - 12) / 12;
            const int i = (g - 12) % 12;
            const int ntok = t + 1;
            if (g == 12) {
                // encoder tail -> M regs; O init; X = O per lane
                float4 xa = s.x4[e][q];
                float f0 = fr3(s.fred[e][q][0]);
                float f1 = fr3(s.fred[e][q][1]);
                float f2 = fr3(s.fred[e][q][2]);
                float o0, o1, o2;
                ln3s(xa.x + f0 + enc_l2_b[33], xa.y + f1 + enc_l2_b[34],
                     xa.z + f2 + enc_l2_b[35], enc_n2_w + 33, enc_n2_b + 33,
                     o0, o1, o2);
                ln3s(o0, o1, o2, enc_nf_w, enc_nf_b, M0, M1, M2);
                O0 = (q == 0) ? E0 : 0.f;
                O1 = (q == 0) ? E1 : 0.f;
                O2 = (q == 0) ? E2 : 0.f;
                X0 = O0; X1 = O1; X2 = O2;
            } else if (i == 0) {
                // step-tail fold: lane q==t-1 updates O from prev step
                if (q == t-1) {
                    float4 xa = s.x4[e][q];
                    float f0 = fr3(s.fred[e][q][0]);
                    float f1 = fr3(s.fred[e][q][1]);
                    float f2 = fr3(s.fred[e][q][2]);
                    float o0, o1, o2;
                    ln3s(xa.x + f0 + dec_l2_b[33], xa.y + f1 + dec_l2_b[34],
                         xa.z + f2 + dec_l2_b[35], dec_n3_w + 33, dec_n3_b + 33,
                         o0, o1, o2);
                    ln3s(o0, o1, o2, dec_nf_w, dec_nf_b, O0, O1, O2);
                }
                const bool rl = (q <= t-1);
                X0 = rl ? O0 : 0.f; X1 = rl ? O1 : 0.f; X2 = rl ? O2 : 0.f;
            } else {
                float4 xa = s.x4[e][q];
                float f0 = fr3(s.fred[e][q][0]);
                float f1 = fr3(s.fred[e][q][1]);
                float f2 = fr3(s.fred[e][q][2]);
                ln3s(xa.x + f0 + dec_l2_b[(i-1)*3+0],
                     xa.y + f1 + dec_l2_b[(i-1)*3+1],
                     xa.z + f2 + dec_l2_b[(i-1)*3+2],
                     dec_n3_w + (i-1)*3, dec_n3_b + (i-1)*3, X0, X1, X2);
            }
            const float* saw = dec_sa_w + i*27;
            const float* sab = dec_sa_b + i*9;
            const float* caw = dec_ca_w + i*27;
            const float* cab = dec_ca_b + i*9;
            if (lane < 32) {
                if (q < ntok) {
                    #pragma unroll
                    for (int h = 0; h < 3; ++h) {
                        s.kk[e][h][q] = sab[3+h] + saw[9+3*h]*X0  + saw[10+3*h]*X1 + saw[11+3*h]*X2;
                        s.vv[e][h][q] = sab[6+h] + saw[18+3*h]*X0 + saw[19+3*h]*X1 + saw[20+3*h]*X2;
                    }
                }
                #pragma unroll
                for (int h = 0; h < 3; ++h) {
                    s.cak[e][h][q] = cab[3+h] + caw[(3+h)*3]*M0 + caw[(3+h)*3+1]*M1 + caw[(3+h)*3+2]*M2;
                    s.cav[e][h][q] = cab[6+h] + caw[(6+h)*3]*M0 + caw[(6+h)*3+1]*M1 + caw[(6+h)*3+2]*M2;
                }
            }
            float oh[3];
            #pragma unroll
            for (int h = 0; h < 3; ++h) {
                float qv = (sab[h] + saw[3*h]*X0 + saw[3*h+1]*X1 + saw[3*h+2]*X2) * LOG2E;
                oh[h] = attn_half<true>(qv, &s.kk[e][h][0], &s.vv[e][h][0],
                                        half, ntok, t, (float)(TT - t));
            }
            const float* saow = dec_sa_ow + i*9;
            const float* saob = dec_sa_ob + i*3;
            float y0 = X0 + saob[0] + saow[0]*oh[0] + saow[1]*oh[1] + saow[2]*oh[2];
            float y1 = X1 + saob[1] + saow[3]*oh[0] + saow[4]*oh[1] + saow[5]*oh[2];
            float y2 = X2 + saob[2] + saow[6]*oh[0] + saow[7]*oh[1] + saow[8]*oh[2];
            float B0, B1, B2;
            ln3s(y0, y1, y2, dec_n1_w + i*3, dec_n1_b + i*3, B0, B1, B2);
            float oc[3];
            #pragma unroll
            for (int h = 0; h < 3; ++h) {
                float cqv = (cab[h] + caw[3*h]*B0 + caw[3*h+1]*B1 + caw[3*h+2]*B2) * LOG2E;
                oc[h] = attn_half<false>(cqv, &s.cak[e][h][0], &s.cav[e][h][0],
                                         half, TT, -1, 1.f);
            }
            const float* caow = dec_ca_ow + i*9;
            const float* caob = dec_ca_ob + i*3;
            float z0 = B0 + caob[0] + caow[0]*oc[0] + caow[1]*oc[1] + caow[2]*oc[2];
            float z1 = B1 + caob[1] + caow[3]*oc[0] + caow[4]*oc[1] + caow[5]*oc[2];
            float z2 = B2 + caob[2] + caow[6]*oc[0] + caow[7]*oc[1] + caow[8]*oc[2];
            float A0, A1, A2;
            ln3s(z0, z1, z2, dec_n2_w + i*3, dec_n2_b + i*3, A0, A1, A2);
            if (lane < 32 && q < ntok) s.x4[e][q] = make_float4(A0, A1, A2, 0.f);
        }
        __builtin_amdgcn_s_setprio(0);
    };

    // ------ full FFN for (layer L, element e), self-contained ------
    auto FFN = [&](int L, int e) {
        const int ntokF = (L < 12) ? TT : (2 + (L - 12) / 12);
        const float4* wb = s.wbuf[L & 1];
        if (ntokF <= 8)       ffn_pass<2>(s, e, wb, gi, w3, flane, lane, 0);
        else if (ntokF <= 16) ffn_pass<4>(s, e, wb, gi, w3, flane, lane, 0);
        else { ffn_pass<4>(s, e, wb, gi, w3, flane, lane, 0);
               ffn_pass<4>(s, e, wb, gi, w3, flane, lane, 4); }
    };

    // ------ stage one 16KB quarter: half hs of layer L (wv 14/15) ------
    auto STAGE = [&](int L, int hs) {
        const int wi = (L < 12) ? L : 12 + (L - 12) % 12;
        const float4* sp = w_all + (size_t)wi*4096 + hs*2048 + (size_t)(wv-14)*1024;
        float4* dp = s.wbuf[L & 1] + hs*2048 + (wv-14)*1024;
        #pragma unroll 4
        for (int j = 0; j < 16; ++j)
            dp[j*64 + lane] = sp[j*64 + lane];
    };

    // ------ main staggered loop ------
    for (int g = 0; g <= 384; ++g) {
        // slot 0
        if (wv == 0)                 { if (g < 384) ATTN(g); }
        else if (wv >= 2 && wv < 14) { if (g >= 1)  FFN(g - 1, 1); }
        else if (wv >= 14)           { if (g >= 1 && g < 384) STAGE(g, 1); }
        __syncthreads();
        if (g == 384) break;
        // slot 1
        if (wv == 1)                 ATTN(g);
        else if (wv >= 2 && wv < 14) FFN(g, 0);
        else if (wv >= 14)           { if (g + 1 <= 383) STAGE(g + 1, 0); }
        __syncthreads();
    }

    // ---- final token-31 fold + output writes (each attn wave: its element)
    if (wv < 2) {
        const int e = wv;
        if (q == 31) {
            float4 xa = s.x4[e][31];
            float f0 = fr3(s.fred[e][31][0]);
            float f1 = fr3(s.fred[e][31][1]);
            float f2 = fr3(s.fred[e][31][2]);
            float o0, o1, o2;
            ln3s(xa.x + f0 + dec_l2_b[33], xa.y + f1 + dec_l2_b[34],
                 xa.z + f2 + dec_l2_b[35], dec_n3_w + 33, dec_n3_b + 33,
                 o0, o1, o2);
            ln3s(o0, o1, o2, dec_nf_w, dec_nf_b, O0, O1, O2);
        }
        if (lane < 32) {
            out[(b0+e)*96 +  0 + q] = O0;
            out[(b0+e)*96 + 32 + q] = O1;
            out[(b0+e)*96 + 64 + q] = O2;
        }
    }
}

extern "C" void kernel_launch(void* const* d_in, const int* in_sizes, int n_in,
                              void* d_out, int out_size, void* d_ws, size_t ws_size,
                              hipStream_t stream) {
    const float* src      = (const float*)d_in[0];
    const float* angle    = (const float*)d_in[1];
    const float* enc_sa_w = (const float*)d_in[2];
    const float* enc_sa_b = (const float*)d_in[3];
    const float* enc_sa_ow= (const float*)d_in[4];
    const float* enc_sa_ob= (const float*)d_in[5];
    const float* enc_l1_w = (const float*)d_in[6];
    const float* enc_l1_b = (const float*)d_in[7];
    const float* enc_l2_w = (const float*)d_in[8];
    const float* enc_l2_b = (const float*)d_in[9];
    const float* enc_n1_w = (const float*)d_in[10];
    const float* enc_n1_b = (const float*)d_in[11];
    const float* enc_n2_w = (const float*)d_in[12];
    const float* enc_n2_b = (const float*)d_in[13];
    const float* enc_nf_w = (const float*)d_in[14];
    const float* enc_nf_b = (const float*)d_in[15];
    const float* dec_sa_w = (const float*)d_in[16];
    const float* dec_sa_b = (const float*)d_in[17];
    const float* dec_sa_ow= (const float*)d_in[18];
    const float* dec_sa_ob= (const float*)d_in[19];
    const float* dec_ca_w = (const float*)d_in[20];
    const float* dec_ca_b = (const float*)d_in[21];
    const float* dec_ca_ow= (const float*)d_in[22];
    const float* dec_ca_ob= (const float*)d_in[23];
    const float* dec_l1_w = (const float*)d_in[24];
    const float* dec_l1_b = (const float*)d_in[25];
    const float* dec_l2_w = (const float*)d_in[26];
    const float* dec_l2_b = (const float*)d_in[27];
    const float* dec_n1_w = (const float*)d_in[28];
    const float* dec_n1_b = (const float*)d_in[29];
    const float* dec_n2_w = (const float*)d_in[30];
    const float* dec_n2_b = (const float*)d_in[31];
    const float* dec_n3_w = (const float*)d_in[32];
    const float* dec_n3_b = (const float*)d_in[33];
    const float* dec_nf_w = (const float*)d_in[34];
    const float* dec_nf_b = (const float*)d_in[35];

    float4* w_all = (float4*)d_ws;

    prepack_kernel<<<(24 * 1024 + 255) / 256, 256, 0, stream>>>(
        enc_l1_w, enc_l1_b, enc_l2_w,
        dec_l1_w, dec_l1_b, dec_l2_w,
        w_all);

    seq_kernel<<<NB/2, 1024, 0, stream>>>(
        src, angle,
        enc_sa_w, enc_sa_b, enc_sa_ow, enc_sa_ob, enc_l2_b,
        enc_n1_w, enc_n1_b, enc_n2_w, enc_n2_b, enc_nf_w, enc_nf_b,
        dec_sa_w, dec_sa_b, dec_sa_ow, dec_sa_ob,
        dec_ca_w, dec_ca_b, dec_ca_ow, dec_ca_ob, dec_l2_b,
        dec_n1_w, dec_n1_b, dec_n2_w, dec_n2_b, dec_n3_w, dec_n3_b,
        dec_nf_w, dec_nf_b,
        (const float4*)w_all,
        (float*)d_out);
}